// Round 5
// baseline (252.472 us; speedup 1.0000x reference)
//
#include <hip/hip_runtime.h>

typedef short short8 __attribute__((ext_vector_type(8)));
typedef float f32x16 __attribute__((ext_vector_type(16)));

// Problem constants
#define BATCH 4096
#define IN_F 256
#define OUT_F 256
#define HYP 128
#define HX 129               // HYP + 1 (b2g folded in as extra channel, gain 1.0)
#define NGRP (HX * 16)       // 2064 fragment groups (h, i-half, k16-tile)
#define NBV (NGRP * 2)       // 4128 buildV blocks in k_prep

__device__ __forceinline__ float bf2f(unsigned short u) {
  unsigned v = ((unsigned)u) << 16;
  float f;
  __builtin_memcpy(&f, &v, 4);
  return f;
}
__device__ __forceinline__ unsigned short f2bf(float f) {
  unsigned u;
  __builtin_memcpy(&u, &f, 4);
  unsigned r = u + 0x7fffu + ((u >> 16) & 1u);  // RTNE
  return (unsigned short)(r >> 16);
}

// ---------------------------------------------------------------------------
// k_prep: merged buildV (blocks 0..NBV-1) + pre (blocks NBV..NBV+255).
// buildV: MFMA-fragment-native layout.
//   Group g = h*16 + ihh*8 + tk  (ihh = i-half, tk = k16-tile within half).
//   VL4[g*512 + o*2 + hi] = bf16x8 of V[o][i = ihh*128 + tk*16 + hi*8 ..+8]
//   where V[o][h*256+i] = (h<128 ? W2g[h][o*256+i] : b2g[o*256+i]).
//   => k_gemm's per-wave fragment load (lane=hi*32+l31, o=o0+l31) is a
//      fully-coalesced contiguous 1 KB global_load_dwordx4.
// pre: hg -> eps-clamped bf16 transposed [h][b] (+row 128 = 1.0); hb;
//      bias GEMM initializes d_out; x -> bf16.
// ---------------------------------------------------------------------------
__global__ __launch_bounds__(256) void k_prep(const float* __restrict__ x,
                                              const float* __restrict__ W1g, const float* __restrict__ b1g,
                                              const float* __restrict__ W2g, const float* __restrict__ b2g,
                                              const float* __restrict__ W1b, const float* __restrict__ b1b,
                                              const float* __restrict__ W2b, const float* __restrict__ b2b,
                                              unsigned short* __restrict__ VL,
                                              unsigned short* __restrict__ hgsT,
                                              unsigned short* __restrict__ xb,
                                              float* __restrict__ out) {
  __shared__ float xl[16 * IN_F];                 // 16 KB
  __shared__ float hbl[16 * HYP];                 // 8 KB  [row][h]
  __shared__ unsigned short hgt[HYP * 16];        // 4 KB  [h][row]
  const int t = threadIdx.x;

  if (blockIdx.x < NBV) {
    // ---------------- buildV (fragment-native layout) ----------------
    const int g = blockIdx.x >> 1;                // group 0..2063
    const int u = (blockIdx.x & 1) * 256 + t;     // 0..511 within group
    const int h = g >> 4;
    const int ihh = (g >> 3) & 1;
    const int tk = g & 7;
    const int o = u >> 1;
    const int hi2 = u & 1;
    const int isrc = ihh * 128 + tk * 16 + hi2 * 8;
    const float* src = (h < HYP) ? (W2g + (size_t)h * (OUT_F * IN_F) + o * IN_F + isrc)
                                 : (b2g + o * IN_F + isrc);
    const float4 v0 = ((const float4*)src)[0];
    const float4 v1 = ((const float4*)src)[1];
    uint4 pk;
    pk.x = (unsigned)f2bf(v0.x) | ((unsigned)f2bf(v0.y) << 16);
    pk.y = (unsigned)f2bf(v0.z) | ((unsigned)f2bf(v0.w) << 16);
    pk.z = (unsigned)f2bf(v1.x) | ((unsigned)f2bf(v1.y) << 16);
    pk.w = (unsigned)f2bf(v1.z) | ((unsigned)f2bf(v1.w) << 16);
    ((uint4*)VL)[(size_t)g * 512 + u] = pk;       // coalesced write
    return;
  }

  // ---------------- pre ----------------
  const int r0 = (blockIdx.x - NBV) * 16;
  for (int j0 = 0; j0 < 16 * IN_F; j0 += 256) {
    const float v = x[(size_t)r0 * IN_F + j0 + t];
    xl[j0 + t] = v;
    xb[(size_t)r0 * IN_F + j0 + t] = f2bf(v);
  }
  __syncthreads();
  const int h = t & 127;
  const int rb = (t >> 7) * 8;
  float ag[8] = {0.f, 0.f, 0.f, 0.f, 0.f, 0.f, 0.f, 0.f};
  float av[8] = {0.f, 0.f, 0.f, 0.f, 0.f, 0.f, 0.f, 0.f};
  for (int i = 0; i < IN_F; ++i) {
    const float wg = W1g[i * HYP + h];
    const float wb = W1b[i * HYP + h];
#pragma unroll
    for (int r = 0; r < 8; ++r) {
      const float xv = xl[(rb + r) * IN_F + i];
      ag[r] += xv * wg;
      av[r] += xv * wb;
    }
  }
  const float bg = b1g[h], bb = b1b[h];
#pragma unroll
  for (int r = 0; r < 8; ++r) {
    float g = ag[r] + bg; g = g > 0.f ? g : 0.f;
    float v = av[r] + bb; v = v > 0.f ? v : 0.f;
    g = g > 1e-20f ? g : 1e-20f;  // eps-clamp: running-rescale divides by hg
    hgt[h * 16 + rb + r] = f2bf(g);
    hbl[(rb + r) * HYP + h] = v;
  }
  __syncthreads();
  {  // transposed store: hgsT[h][r0..r0+16)
    const int h2 = t >> 1, part = t & 1;
    const uint4 pk = *(const uint4*)&hgt[h2 * 16 + part * 8];
    *(uint4*)&hgsT[(size_t)h2 * BATCH + r0 + part * 8] = pk;
  }
  if (t < 16) hgsT[(size_t)HYP * BATCH + r0 + t] = 0x3F80;  // row 128 = 1.0
  // out init: out[r0+r][o=t] = b2b + sum_h hb*W2b
  float acc[16];
#pragma unroll
  for (int r = 0; r < 16; ++r) acc[r] = 0.f;
  for (int hh = 0; hh < HYP; ++hh) {
    const float w = W2b[hh * OUT_F + t];
#pragma unroll
    for (int r = 0; r < 16; ++r) acc[r] += hbl[r * HYP + hh] * w;
  }
  const float bo = b2b[t];
#pragma unroll
  for (int r = 0; r < 16; ++r) out[(size_t)(r0 + r) * OUT_F + t] = acc[r] + bo;
}

// ---------------------------------------------------------------------------
// k_gemm (C^T): C[m=o, n=b] = sum_h hg[b,h] * (V[o,h,:] . x[b,:])
// BARRIER-FREE K-loop (r2/r4's global_load_lds+syncthreads structure
// plateaued 3x at ~26% MfmaUtil from barrier-lockstep vmcnt(0) drains):
//   V fragments double-buffered in REGISTERS, prefetched one round (1 h)
//   ahead via coalesced global_load_dwordx4 from the fragment-native VL
//   layout; compiler emits fine-grained vmcnt; waves run free.
// Per wave Mo=32 x Nb=64: xf[2][8]=64 VGPR, vaA+vaB=64, acc=32 -> ~180 regs.
// hg in LDS (read-only after one prologue barrier), prefetched 1 round
// ahead; per-lane running rescale u *= hg[h-1]/hg[h] (validated r3/r4).
// Grid (8 o, 16 b, 4 z=(h-half,i-half)) = 512 blocks = 2/CU, 2 waves/SIMD.
// Epilogue: LDS transpose (pad 34) + coalesced float-quad atomicAdd.
// ---------------------------------------------------------------------------
__global__ __launch_bounds__(256, 2) void k_gemm(const unsigned short* __restrict__ VL,
                                                 const unsigned short* __restrict__ hgsT,
                                                 const unsigned short* __restrict__ xb,
                                                 float* __restrict__ out) {
  // hgs: 65*256 shorts = 33280 B; epilogue tep: 256*34 floats = 34816 B
  __shared__ __align__(16) unsigned short smem[17408];
  unsigned short* hgs = smem;
  float* tep = (float*)smem;

  const int tid = threadIdx.x;
  const int lane = tid & 63;
  const int wave = tid >> 6;
  const int l31 = lane & 31;
  const int hi = lane >> 5;
  const int o0 = blockIdx.x * 32;
  const int b0 = blockIdx.y * 256;
  const int zh = blockIdx.z & 1;
  const int zi = blockIdx.z >> 1;
  const int hBeg = zh ? 64 : 0;
  const int nh = zh ? (HX - 64) : 64;   // 65 or 64
  const int ih = zi * 128;

  // V fragment lane base: group g = (hBeg+r)*16 + zi*8 + t; shorts offset
  // = g*4096 + (o0+l31)*16 + hi*8  (contiguous 1 KB per wave per load)
  const unsigned short* vbase =
      VL + (size_t)(o0 + l31) * 16 + hi * 8 + (size_t)zi * 8 * 4096;

  // ---- preload x fragments: 2 n-subtiles x 8 k16 (64 VGPR) ----
  const int bw = b0 + wave * 64;
  uint4 xf0[8], xf1[8];
#pragma unroll
  for (int t = 0; t < 8; ++t) {
    xf0[t] = *(const uint4*)(xb + (size_t)(bw + l31) * IN_F + ih + t * 16 + hi * 8);
    xf1[t] = *(const uint4*)(xb + (size_t)(bw + 32 + l31) * IN_F + ih + t * 16 + hi * 8);
  }

  // ---- stage hg tile [h_local][b] -> LDS ----
  for (int idx = tid; idx < nh * 32; idx += 256) {
    const int hl = idx >> 5, c8 = (idx & 31) * 8;
    *(uint4*)&hgs[hl * 256 + c8] =
        *(const uint4*)&hgsT[(size_t)(hBeg + hl) * BATCH + b0 + c8];
  }

  // ---- prefetch V round 0 into buffer A ----
  uint4 vaA[8], vaB[8];
#pragma unroll
  for (int t = 0; t < 8; ++t)
    vaA[t] = *(const uint4*)(vbase + (size_t)((hBeg * 16 + zi * 8 + t) - zi * 8) * 4096);
  // note: zi folded into vbase already; offset is (hBeg*16 + t)*4096

  __syncthreads();  // hgs ready (the ONLY barrier before the epilogue)

  f32x16 zv;
#pragma unroll
  for (int i = 0; i < 16; ++i) zv[i] = 0.0f;
  f32x16 acc0 = zv, acc1 = zv;

  const int hgoff = wave * 64 + l31;
  float hgc0 = bf2f(hgs[hgoff]);        // row 0 (scale state: last applied)
  float hgc1 = bf2f(hgs[hgoff + 32]);
  float hgn0 = hgc0, hgn1 = hgc1;       // value of current row r

  auto load_v = [&](uint4 (&buf)[8], int r) {
    const unsigned short* p = vbase + (size_t)(hBeg + r) * 16 * 4096;
#pragma unroll
    for (int t = 0; t < 8; ++t)
      buf[t] = *(const uint4*)(p + (size_t)t * 4096);
  };

  auto body = [&](uint4 (&vc)[8], int r) {
    // prefetch hg row r+1 (used next round)
    float hq0 = 0.f, hq1 = 0.f;
    if (r + 1 < nh) {
      hq0 = bf2f(hgs[(r + 1) * 256 + hgoff]);
      hq1 = bf2f(hgs[(r + 1) * 256 + hgoff + 32]);
    }
    if (r) {  // rescale: u *= hg[r-1]/hg[r]
      const float rt0 = hgc0 * __builtin_amdgcn_rcpf(hgn0);
      const float rt1 = hgc1 * __builtin_amdgcn_rcpf(hgn1);
      hgc0 = hgn0; hgc1 = hgn1;
#pragma unroll
      for (int g = 0; g < 16; ++g) {
        acc0[g] *= rt0;
        acc1[g] *= rt1;
      }
    }
#pragma unroll
    for (int t = 0; t < 8; ++t) {
      acc0 = __builtin_amdgcn_mfma_f32_32x32x16_bf16(
          __builtin_bit_cast(short8, vc[t]), __builtin_bit_cast(short8, xf0[t]), acc0, 0, 0, 0);
      acc1 = __builtin_amdgcn_mfma_f32_32x32x16_bf16(
          __builtin_bit_cast(short8, vc[t]), __builtin_bit_cast(short8, xf1[t]), acc1, 0, 0, 0);
    }
    hgn0 = hq0; hgn1 = hq1;
  };

  int r = 0;
  for (; r + 2 <= nh; r += 2) {
    load_v(vaB, r + 1);                 // prefetch r+1 under r's MFMAs
    body(vaA, r);
    if (r + 2 < nh) load_v(vaA, r + 2); // prefetch r+2 under r+1's MFMAs
    body(vaB, r + 1);
  }
  if (r < nh) body(vaA, r);             // odd tail (nh=65)

  // final scale: u *= hg[nh-1]
#pragma unroll
  for (int g = 0; g < 16; ++g) {
    acc0[g] *= hgc0;
    acc1[g] *= hgc1;
  }

  // ---- epilogue: transpose via LDS (pad 34; aliases hgs - barrier first) ----
  __syncthreads();
  const int bb = wave * 64;
#pragma unroll
  for (int g = 0; g < 16; ++g) {
    const int orow = (g & 3) + 8 * (g >> 2) + 4 * hi;
    tep[(bb + l31) * 34 + orow] = acc0[g];
    tep[(bb + 32 + l31) * 34 + orow] = acc1[g];
  }
  __syncthreads();
  // coalesced atomic accumulate: thread t -> o-quad (t&7)*4, b-rows (t>>3)+32*it
  const int oq = (tid & 7) * 4;
  const int br = tid >> 3;
  for (int it = 0; it < 8; ++it) {
    const int bl = br + 32 * it;
    float* op = &out[(size_t)(b0 + bl) * OUT_F + o0 + oq];
    const float* tp = &tep[bl * 34 + oq];
    atomicAdd(op + 0, tp[0]);
    atomicAdd(op + 1, tp[1]);
    atomicAdd(op + 2, tp[2]);
    atomicAdd(op + 3, tp[3]);
  }
}

// ---------------------------------------------------------------------------
extern "C" void kernel_launch(void* const* d_in, const int* in_sizes, int n_in,
                              void* d_out, int out_size, void* d_ws, size_t ws_size,
                              hipStream_t stream) {
  const float* x = (const float*)d_in[0];
  const float* W1g = (const float*)d_in[1];
  const float* b1g = (const float*)d_in[2];
  const float* W2g = (const float*)d_in[3];
  const float* b2g = (const float*)d_in[4];
  const float* W1b = (const float*)d_in[5];
  const float* b1b = (const float*)d_in[6];
  const float* W2b = (const float*)d_in[7];
  const float* b2b = (const float*)d_in[8];
  float* out = (float*)d_out;

  char* ws = (char*)d_ws;
  const size_t szV = (size_t)NGRP * 512 * 16;       // 16,908,288 B
  const size_t szHg = (size_t)HX * BATCH * 2;       //  1,056,768 B (129 rows)
  unsigned short* VL = (unsigned short*)ws;
  unsigned short* hgsT = (unsigned short*)(ws + szV);
  unsigned short* xb = (unsigned short*)(ws + szV + szHg);

  hipLaunchKernelGGL(k_prep, dim3(NBV + BATCH / 16), dim3(256), 0, stream,
                     x, W1g, b1g, W2g, b2g, W1b, b1b, W2b, b2b, VL, hgsT, xb, out);
  hipLaunchKernelGGL(k_gemm, dim3(OUT_F / 32, BATCH / 256, 4), dim3(256), 0, stream,
                     VL, hgsT, xb, out);
}